// Round 1
// baseline (666.533 us; speedup 1.0000x reference)
//
#include <hip/hip_runtime.h>
#include <cstdint>

typedef __attribute__((ext_vector_type(8))) short short8;
typedef __attribute__((ext_vector_type(4))) float floatx4;
typedef unsigned short u16;

#define D_MODEL 1024
#define S_LEN 4096
#define N_HEADS 16
#define HEAD_DIM 64

__device__ __forceinline__ u16 f2bf(float x) {
    union { float f; uint32_t u; } v; v.f = x;
    uint32_t u = v.u;
    u += 0x7fffu + ((u >> 16) & 1u);
    return (u16)(u >> 16);
}

// ---------------- elementwise fp32 -> bf16 ----------------
__global__ __launch_bounds__(256) void convert_f32_bf16(const float* __restrict__ src,
                                                        u16* __restrict__ dst, int n4) {
    int i = blockIdx.x * 256 + threadIdx.x;
    if (i >= n4) return;
    float4 v = reinterpret_cast<const float4*>(src)[i];
    ushort4 o;
    o.x = f2bf(v.x); o.y = f2bf(v.y); o.z = f2bf(v.z); o.w = f2bf(v.w);
    reinterpret_cast<ushort4*>(dst)[i] = o;
}

// ---------------- tiled transpose (+convert): out[c][r] = in[r][c] ----------------
__global__ __launch_bounds__(256) void transpose_f32_bf16(const float* __restrict__ in,
                                                          u16* __restrict__ out, int R, int C) {
    __shared__ u16 tile[32][34];
    const int tx = threadIdx.x, ty = threadIdx.y;
    const int c0 = blockIdx.x * 32, r0 = blockIdx.y * 32;
    #pragma unroll
    for (int j = 0; j < 32; j += 8)
        tile[ty + j][tx] = f2bf(in[(size_t)(r0 + ty + j) * C + c0 + tx]);
    __syncthreads();
    #pragma unroll
    for (int j = 0; j < 32; j += 8)
        out[(size_t)(c0 + ty + j) * R + r0 + tx] = tile[tx][ty + j];
}

__global__ __launch_bounds__(256) void transpose_bf16(const u16* __restrict__ in,
                                                      u16* __restrict__ out, int R, int C) {
    __shared__ u16 tile[32][34];
    const int tx = threadIdx.x, ty = threadIdx.y;
    const int c0 = blockIdx.x * 32, r0 = blockIdx.y * 32;
    #pragma unroll
    for (int j = 0; j < 32; j += 8)
        tile[ty + j][tx] = in[(size_t)(r0 + ty + j) * C + c0 + tx];
    __syncthreads();
    #pragma unroll
    for (int j = 0; j < 32; j += 8)
        out[(size_t)(c0 + ty + j) * R + r0 + tx] = tile[tx][ty + j];
}

// ---------------- bf16 GEMM: C[M,N] = A[M,K] @ Bt[N,K]^T + bias ----------------
// 128x128 block tile, BK=64, 4 waves each doing 64x64 via 4x4 16x16x32 MFMA frags.
template <typename OutT>
__device__ __forceinline__ void gemm_bt_core(const u16* __restrict__ A, const u16* __restrict__ Bt,
                                             const float* __restrict__ bias, OutT* __restrict__ C,
                                             int M, int N, int K, int bx, int by) {
    constexpr int LDT = 72;  // 64 + 8 pad (bf16 units); row stride 144B (16B-aligned, 2-way banks)
    __shared__ u16 As[128 * LDT];
    __shared__ u16 Bs[128 * LDT];
    const int tid = threadIdx.x;
    const int wave = tid >> 6, lane = tid & 63;
    const int quad = lane >> 4, n16 = lane & 15;
    const int wm = wave >> 1, wn = wave & 1;
    const int m0 = by * 128, n0 = bx * 128;

    floatx4 acc[4][4];
    #pragma unroll
    for (int i = 0; i < 4; ++i)
        #pragma unroll
        for (int t = 0; t < 4; ++t) acc[i][t] = (floatx4)0.f;

    for (int kt = 0; kt < K; kt += 64) {
        __syncthreads();
        #pragma unroll
        for (int u = 0; u < 4; ++u) {
            const int c = tid + u * 256;          // 1024 chunks of 8 bf16 (16B)
            const int row = c >> 3, off = (c & 7) * 8;
            *reinterpret_cast<float4*>(&As[row * LDT + off]) =
                *reinterpret_cast<const float4*>(&A[(size_t)(m0 + row) * K + kt + off]);
            *reinterpret_cast<float4*>(&Bs[row * LDT + off]) =
                *reinterpret_cast<const float4*>(&Bt[(size_t)(n0 + row) * K + kt + off]);
        }
        __syncthreads();
        #pragma unroll
        for (int kk = 0; kk < 2; ++kk) {
            short8 a[4], b[4];
            #pragma unroll
            for (int i = 0; i < 4; ++i)
                a[i] = *reinterpret_cast<const short8*>(&As[(wm * 64 + i * 16 + n16) * LDT + kk * 32 + quad * 8]);
            #pragma unroll
            for (int t = 0; t < 4; ++t)
                b[t] = *reinterpret_cast<const short8*>(&Bs[(wn * 64 + t * 16 + n16) * LDT + kk * 32 + quad * 8]);
            #pragma unroll
            for (int i = 0; i < 4; ++i)
                #pragma unroll
                for (int t = 0; t < 4; ++t)
                    acc[i][t] = __builtin_amdgcn_mfma_f32_16x16x32_bf16(a[i], b[t], acc[i][t], 0, 0, 0);
        }
    }
    // epilogue: D layout col=lane&15, row=quad*4+reg
    #pragma unroll
    for (int t = 0; t < 4; ++t) {
        const int col = n0 + wn * 64 + t * 16 + n16;
        const float bv = bias[col];
        #pragma unroll
        for (int i = 0; i < 4; ++i) {
            #pragma unroll
            for (int r = 0; r < 4; ++r) {
                const int row = m0 + wm * 64 + i * 16 + quad * 4 + r;
                const float val = acc[i][t][r] + bv;
                if constexpr (sizeof(OutT) == 2) C[(size_t)row * N + col] = f2bf(val);
                else                             C[(size_t)row * N + col] = val;
            }
        }
    }
}

struct QkvArgs {
    const u16* A[3]; const u16* B[3]; const float* bias[3]; u16* C[3];
};

__global__ __launch_bounds__(256) void gemm_qkv(QkvArgs args, int M, int N, int K) {
    const int z = blockIdx.z;
    gemm_bt_core<u16>(args.A[z], args.B[z], args.bias[z], args.C[z], M, N, K, blockIdx.x, blockIdx.y);
}

__global__ __launch_bounds__(256) void gemm_out(const u16* __restrict__ A, const u16* __restrict__ Bt,
                                                const float* __restrict__ bias, float* __restrict__ C,
                                                int M, int N, int K) {
    gemm_bt_core<float>(A, Bt, bias, C, M, N, K, blockIdx.x, blockIdx.y);
}

// ---------------- flash attention ----------------
// grid (S/64, H); 4 waves/block; wave owns 16 Q rows. K read row-major [s][D_MODEL],
// V read transposed [D_MODEL][s] so both B-operands are contiguous 16B global loads.
__global__ __launch_bounds__(256) void flash_attn(const u16* __restrict__ Q, const u16* __restrict__ Kb,
                                                  const u16* __restrict__ Vt, const int* __restrict__ mask,
                                                  u16* __restrict__ O) {
    __shared__ u16 Ps[4][16 * 72];  // per-wave P strip, row stride 72 bf16 (144B)
    const int tid = threadIdx.x;
    const int wave = tid >> 6, lane = tid & 63;
    const int quad = lane >> 4, n16 = lane & 15;
    const int h = blockIdx.y;
    const int q0 = blockIdx.x * 64 + wave * 16;

    short8 a_q[2];
    #pragma unroll
    for (int kk = 0; kk < 2; ++kk)
        a_q[kk] = *reinterpret_cast<const short8*>(
            &Q[(size_t)(q0 + n16) * D_MODEL + h * HEAD_DIM + kk * 32 + quad * 8]);

    float m_i[4], l_i[4];
    floatx4 o_acc[4];
    #pragma unroll
    for (int r = 0; r < 4; ++r) { m_i[r] = -__builtin_inff(); l_i[r] = 0.f; }
    #pragma unroll
    for (int t = 0; t < 4; ++t) o_acc[t] = (floatx4)0.f;

    for (int k0 = 0; k0 < S_LEN; k0 += 64) {
        // S = Q K^T (16 rows x 64 keys per wave)
        floatx4 s[4];
        #pragma unroll
        for (int t = 0; t < 4; ++t) {
            s[t] = (floatx4)0.f;
            #pragma unroll
            for (int kk = 0; kk < 2; ++kk) {
                short8 bk = *reinterpret_cast<const short8*>(
                    &Kb[(size_t)(k0 + t * 16 + n16) * D_MODEL + h * HEAD_DIM + kk * 32 + quad * 8]);
                s[t] = __builtin_amdgcn_mfma_f32_16x16x32_bf16(a_q[kk], bk, s[t], 0, 0, 0);
            }
        }
        // scale + mask
        float sv[4][4];
        #pragma unroll
        for (int t = 0; t < 4; ++t) {
            const float msk = (mask[k0 + t * 16 + n16] == 0) ? -1.0e9f : 0.f;
            #pragma unroll
            for (int r = 0; r < 4; ++r) sv[t][r] = s[t][r] * 0.125f + msk;
        }
        // online softmax stats (rows live in quad: row = quad*4 + r)
        float tm[4];
        #pragma unroll
        for (int r = 0; r < 4; ++r)
            tm[r] = fmaxf(fmaxf(sv[0][r], sv[1][r]), fmaxf(sv[2][r], sv[3][r]));
        #pragma unroll
        for (int off = 1; off < 16; off <<= 1)
            #pragma unroll
            for (int r = 0; r < 4; ++r) tm[r] = fmaxf(tm[r], __shfl_xor(tm[r], off));
        float alpha[4], rs[4];
        #pragma unroll
        for (int r = 0; r < 4; ++r) {
            const float mn = fmaxf(m_i[r], tm[r]);
            alpha[r] = __expf(m_i[r] - mn);
            m_i[r] = mn;
            rs[r] = 0.f;
        }
        float p[4][4];
        #pragma unroll
        for (int t = 0; t < 4; ++t)
            #pragma unroll
            for (int r = 0; r < 4; ++r) { p[t][r] = __expf(sv[t][r] - m_i[r]); rs[r] += p[t][r]; }
        #pragma unroll
        for (int off = 1; off < 16; off <<= 1)
            #pragma unroll
            for (int r = 0; r < 4; ++r) rs[r] += __shfl_xor(rs[r], off);
        #pragma unroll
        for (int r = 0; r < 4; ++r) l_i[r] = l_i[r] * alpha[r] + rs[r];
        #pragma unroll
        for (int t = 0; t < 4; ++t)
            #pragma unroll
            for (int r = 0; r < 4; ++r) o_acc[t][r] *= alpha[r];
        // P: C-layout -> LDS -> A-layout
        #pragma unroll
        for (int t = 0; t < 4; ++t)
            #pragma unroll
            for (int r = 0; r < 4; ++r)
                Ps[wave][(quad * 4 + r) * 72 + t * 16 + n16] = f2bf(p[t][r]);
        __syncthreads();
        short8 ap[2];
        #pragma unroll
        for (int kk = 0; kk < 2; ++kk)
            ap[kk] = *reinterpret_cast<const short8*>(&Ps[wave][n16 * 72 + kk * 32 + quad * 8]);
        // O += P V
        #pragma unroll
        for (int t = 0; t < 4; ++t) {
            #pragma unroll
            for (int kk = 0; kk < 2; ++kk) {
                short8 bv = *reinterpret_cast<const short8*>(
                    &Vt[(size_t)(h * HEAD_DIM + t * 16 + n16) * S_LEN + k0 + kk * 32 + quad * 8]);
                o_acc[t] = __builtin_amdgcn_mfma_f32_16x16x32_bf16(ap[kk], bv, o_acc[t], 0, 0, 0);
            }
        }
    }
    #pragma unroll
    for (int r = 0; r < 4; ++r) l_i[r] = 1.f / l_i[r];
    #pragma unroll
    for (int t = 0; t < 4; ++t)
        #pragma unroll
        for (int r = 0; r < 4; ++r)
            O[(size_t)(q0 + quad * 4 + r) * D_MODEL + h * HEAD_DIM + t * 16 + n16] =
                f2bf(o_acc[t][r] * l_i[r]);
}

extern "C" void kernel_launch(void* const* d_in, const int* in_sizes, int n_in,
                              void* d_out, int out_size, void* d_ws, size_t ws_size,
                              hipStream_t stream) {
    const float* query = (const float*)d_in[0];
    const float* key   = (const float*)d_in[1];
    const float* value = (const float*)d_in[2];
    const int*   mask  = (const int*)d_in[3];
    const float* Wq = (const float*)d_in[4];
    const float* bq = (const float*)d_in[5];
    const float* Wk = (const float*)d_in[6];
    const float* bk = (const float*)d_in[7];
    const float* Wv = (const float*)d_in[8];
    const float* bv = (const float*)d_in[9];
    const float* Wo = (const float*)d_in[10];
    const float* bo = (const float*)d_in[11];
    float* out = (float*)d_out;

    char* ws = (char*)d_ws;
    const size_t SZ_SD = (size_t)S_LEN * D_MODEL * 2;   // 8 MiB
    const size_t SZ_W  = (size_t)D_MODEL * D_MODEL * 2; // 2 MiB
    u16* qb  = (u16*)(ws);                         // bf16 query   (later reused as VpT)
    u16* kb  = (u16*)(ws + SZ_SD);                 // bf16 key     (later reused as Oa)
    u16* vb  = (u16*)(ws + 2 * SZ_SD);             // bf16 value
    u16* Wqt = (u16*)(ws + 3 * SZ_SD);
    u16* Wkt = (u16*)(ws + 3 * SZ_SD + SZ_W);
    u16* Wvt = (u16*)(ws + 3 * SZ_SD + 2 * SZ_W);
    u16* Wot = (u16*)(ws + 3 * SZ_SD + 3 * SZ_W);
    u16* Qp  = (u16*)(ws + 3 * SZ_SD + 4 * SZ_W);
    u16* Kp  = (u16*)(ws + 4 * SZ_SD + 4 * SZ_W);
    u16* Vp  = (u16*)(ws + 5 * SZ_SD + 4 * SZ_W);
    u16* VpT = qb;  // qb dead after gemm_qkv
    u16* Oa  = kb;  // kb dead after gemm_qkv

    const int n4 = S_LEN * D_MODEL / 4;
    convert_f32_bf16<<<dim3(n4 / 256), 256, 0, stream>>>(query, qb, n4);
    convert_f32_bf16<<<dim3(n4 / 256), 256, 0, stream>>>(key, kb, n4);
    convert_f32_bf16<<<dim3(n4 / 256), 256, 0, stream>>>(value, vb, n4);

    dim3 tb(32, 8);
    transpose_f32_bf16<<<dim3(32, 32), tb, 0, stream>>>(Wq, Wqt, D_MODEL, D_MODEL);
    transpose_f32_bf16<<<dim3(32, 32), tb, 0, stream>>>(Wk, Wkt, D_MODEL, D_MODEL);
    transpose_f32_bf16<<<dim3(32, 32), tb, 0, stream>>>(Wv, Wvt, D_MODEL, D_MODEL);
    transpose_f32_bf16<<<dim3(32, 32), tb, 0, stream>>>(Wo, Wot, D_MODEL, D_MODEL);

    QkvArgs qa;
    qa.A[0] = qb;  qa.A[1] = kb;  qa.A[2] = vb;
    qa.B[0] = Wqt; qa.B[1] = Wkt; qa.B[2] = Wvt;
    qa.bias[0] = bq; qa.bias[1] = bk; qa.bias[2] = bv;
    qa.C[0] = Qp; qa.C[1] = Kp; qa.C[2] = Vp;
    gemm_qkv<<<dim3(8, 32, 3), 256, 0, stream>>>(qa, S_LEN, D_MODEL, D_MODEL);

    transpose_bf16<<<dim3(D_MODEL / 32, S_LEN / 32), tb, 0, stream>>>(Vp, VpT, S_LEN, D_MODEL);

    flash_attn<<<dim3(S_LEN / 64, N_HEADS), 256, 0, stream>>>(Qp, Kp, VpT, mask, Oa);

    gemm_out<<<dim3(8, 32), 256, 0, stream>>>(Oa, Wot, bo, out, S_LEN, D_MODEL, D_MODEL);
}